// Round 1
// baseline (364.822 us; speedup 1.0000x reference)
//
#include <hip/hip_runtime.h>
#include <hip/hip_bf16.h>
#include <math.h>

#define BB 16
#define IC 64
#define CH 128
#define LL 16384
#define KS 5
#define CAK 5
#define KCR 76
#define EPSV 1e-5f
#define NLT 64            // number of L tiles of 256

// ---- workspace layout (in floats) ----
#define OFF_W2    0                         // IC*KS*CH = 40960 (weights repacked [i][k][c], pre-scaled by BN inv)
#define OFF_BIAS2 (OFF_W2 + IC*KS*CH)       // CH
#define OFF_PSUM  (OFF_BIAS2 + CH)          // BB*CH*NLT
#define OFF_PMAX  (OFF_PSUM + BB*CH*NLT)    // BB*CH*NLT
#define OFF_CM    (OFF_PMAX + BB*CH*NLT)    // BB*CH
#define OFF_MASK  (OFF_CM + BB*CH)          // BB*CH
#define OFF_CMAX  (OFF_MASK + BB*CH)        // BB*LL
#define OFF_CAVG  (OFF_CMAX + BB*LL)
#define OFF_SMAX  (OFF_CAVG + BB*LL)
#define OFF_SAVG  (OFF_SMAX + BB*LL)
#define OFF_A1    (OFF_SAVG + BB*LL)
#define OFF_A2    (OFF_A1 + BB*LL)

// ---------------------------------------------------------------------------
// Prep: fold BN scale into conv weights, repack to [i][k][c]; fold bias.
// f = relu( conv(x,w)*inv + (conv_b - m)*inv + b )  with inv = g/sqrt(v+eps)
// ---------------------------------------------------------------------------
__global__ void prep_kernel(const float* __restrict__ conv_w, const float* __restrict__ conv_b,
                            const float* __restrict__ bn_g, const float* __restrict__ bn_b,
                            const float* __restrict__ bn_m, const float* __restrict__ bn_v,
                            float* __restrict__ w2, float* __restrict__ bias2)
{
    int idx = blockIdx.x * 256 + threadIdx.x;
    if (idx < IC * KS * CH) {
        int c  = idx & (CH - 1);
        int ik = idx >> 7;          // i*KS + k
        int i  = ik / KS, k = ik - i * KS;
        float inv = bn_g[c] * rsqrtf(bn_v[c] + EPSV);
        w2[idx] = conv_w[(c * IC + i) * KS + k] * inv;
        if (ik == 0) bias2[c] = (conv_b[c] - bn_m[c]) * inv + bn_b[c];
    }
}

// ---------------------------------------------------------------------------
// Conv + BN + ReLU -> f (written into d_out), plus per-(b,c,ltile) partial
// sum/max for the later channel-attention reductions.
// Grid: (B, NLT). Block: 256 = 4 waves x 64 lanes. Each lane owns 4 l's,
// each wave owns 8 consecutive channels per pass, 4 passes -> 32*4 = 128 ch.
// ---------------------------------------------------------------------------
__global__ __launch_bounds__(256, 2)
void conv_kernel(const float* __restrict__ x, const float* __restrict__ w2,
                 const float* __restrict__ bias2, float* __restrict__ f,
                 float* __restrict__ psum, float* __restrict__ pmax)
{
    __shared__ float xs[IC * 260];   // 66,560 B: 64 rows x (256 + 4 halo)
    const int b  = blockIdx.x;
    const int lt = blockIdx.y;
    const int l0 = lt * 256;

    const float* xb = x + (size_t)b * (IC * LL);
    for (int idx = threadIdx.x; idx < IC * 260; idx += 256) {
        int i  = idx / 260;
        int dl = idx - i * 260;
        int gl = l0 + dl - 2;
        xs[idx] = (gl >= 0 && gl < LL) ? xb[i * LL + gl] : 0.0f;
    }
    __syncthreads();

    const int lane = threadIdx.x & 63;
    const int wv   = __builtin_amdgcn_readfirstlane(threadIdx.x >> 6); // wave id, uniform
    const int ll4  = lane * 4;

    for (int p = 0; p < 4; ++p) {
        const int c0 = p * 32 + wv * 8;   // uniform per wave
        float acc[8][4];
        #pragma unroll
        for (int cc = 0; cc < 8; ++cc)
            #pragma unroll
            for (int j = 0; j < 4; ++j) acc[cc][j] = 0.0f;

        for (int i = 0; i < IC; ++i) {
            float4 xa = *(const float4*)&xs[i * 260 + ll4];
            float4 xc = *(const float4*)&xs[i * 260 + ll4 + 4];
            float xw[8] = {xa.x, xa.y, xa.z, xa.w, xc.x, xc.y, xc.z, xc.w};
            #pragma unroll
            for (int k = 0; k < KS; ++k) {
                const float* wr = w2 + (i * KS + k) * CH + c0;  // uniform -> s_load
                #pragma unroll
                for (int cc = 0; cc < 8; ++cc) {
                    float wvv = wr[cc];
                    acc[cc][0] = fmaf(xw[k + 0], wvv, acc[cc][0]);
                    acc[cc][1] = fmaf(xw[k + 1], wvv, acc[cc][1]);
                    acc[cc][2] = fmaf(xw[k + 2], wvv, acc[cc][2]);
                    acc[cc][3] = fmaf(xw[k + 3], wvv, acc[cc][3]);
                }
            }
        }

        #pragma unroll
        for (int cc = 0; cc < 8; ++cc) {
            int c = c0 + cc;
            float bsc = bias2[c];
            float4 fv;
            fv.x = fmaxf(acc[cc][0] + bsc, 0.0f);
            fv.y = fmaxf(acc[cc][1] + bsc, 0.0f);
            fv.z = fmaxf(acc[cc][2] + bsc, 0.0f);
            fv.w = fmaxf(acc[cc][3] + bsc, 0.0f);
            *(float4*)&f[((size_t)(b * CH + c)) * LL + l0 + ll4] = fv;

            float ts = (fv.x + fv.y) + (fv.z + fv.w);
            float tm = fmaxf(fmaxf(fv.x, fv.y), fmaxf(fv.z, fv.w));
            #pragma unroll
            for (int off = 32; off >= 1; off >>= 1) {
                ts += __shfl_xor(ts, off, 64);
                tm = fmaxf(tm, __shfl_xor(tm, off, 64));
            }
            if (lane == 0) {
                psum[(b * CH + c) * NLT + lt] = ts;
                pmax[(b * CH + c) * NLT + lt] = tm;
            }
        }
    }
}

// ---------------------------------------------------------------------------
// Per-batch: finish L-reductions, channel attention (5-tap conv over C +
// sigmoid), and top-K mask via rank counting (ties broken by lower index,
// matching jax.lax.top_k). Grid: B blocks x 128 threads.
// ---------------------------------------------------------------------------
__global__ void chan_kernel(const float* __restrict__ psum, const float* __restrict__ pmax,
                            const float* __restrict__ alpha, const float* __restrict__ beta,
                            const float* __restrict__ ca_w, const float* __restrict__ ca_b,
                            float* __restrict__ cm, float* __restrict__ maskv)
{
    int b = blockIdx.x;
    int c = threadIdx.x;   // 128
    const float* ps = psum + (b * CH + c) * NLT;
    const float* pm = pmax + (b * CH + c) * NLT;
    float s = 0.0f, m = 0.0f;
    for (int t = 0; t < NLT; ++t) { s += ps[t]; m = fmaxf(m, pm[t]); }
    float favg = s * (1.0f / LL);
    float fadd = (alpha[0] + 0.5f) * favg + (beta[0] + 0.5f) * m;

    __shared__ float fa[CH];
    __shared__ float cms[CH];
    fa[c] = fadd;
    __syncthreads();

    float z = ca_b[0];
    #pragma unroll
    for (int k = 0; k < CAK; ++k) {
        int cc = c + k - 2;
        float v = (cc >= 0 && cc < CH) ? fa[cc] : 0.0f;
        z = fmaf(ca_w[k], v, z);
    }
    float cmv = 1.0f / (1.0f + expf(-z));
    cms[c] = cmv;
    __syncthreads();

    int rank = 0;
    for (int cc = 0; cc < CH; ++cc) {
        float o = cms[cc];
        rank += (o > cmv || (o == cmv && cc < c)) ? 1 : 0;
    }
    cm[b * CH + c] = cmv;
    maskv[b * CH + c] = (rank < KCR) ? 1.0f : 0.0f;
}

// ---------------------------------------------------------------------------
// Per-(b,l) cross-channel group stats of crf = f * channel_map.
// Grid (B, NLT) x 256 threads; thread = one l; loop over 128 channels.
// ---------------------------------------------------------------------------
__global__ __launch_bounds__(256)
void stats_kernel(const float* __restrict__ f, const float* __restrict__ cm,
                  const float* __restrict__ maskv,
                  float* __restrict__ cmaxA, float* __restrict__ cavgA,
                  float* __restrict__ smaxA, float* __restrict__ savgA)
{
    __shared__ float cms[CH], mks[CH];
    int b = blockIdx.x, lt = blockIdx.y;
    int l = lt * 256 + threadIdx.x;
    if (threadIdx.x < CH) {
        cms[threadIdx.x] = cm[b * CH + threadIdx.x];
        mks[threadIdx.x] = maskv[b * CH + threadIdx.x];
    }
    __syncthreads();

    const float* fb = f + (size_t)b * CH * LL + l;
    float cmx = 0.0f, csm = 0.0f, smx = 0.0f, ssm = 0.0f;
    #pragma unroll 4
    for (int c = 0; c < CH; ++c) {
        float v  = fb[(size_t)c * LL] * cms[c];  // crf >= 0
        float mk = mks[c];
        float vs = v * mk;
        float vu = v - vs;
        cmx = fmaxf(cmx, vs);
        smx = fmaxf(smx, vu);
        csm += vs;
        ssm += vu;
    }
    cmaxA[b * LL + l] = cmx;
    cavgA[b * LL + l] = csm * (1.0f / KCR);          // mean*C/KCR = sum/KCR
    smaxA[b * LL + l] = smx;
    savgA[b * LL + l] = ssm * (1.0f / (CH - KCR));   // sum/52
}

// ---------------------------------------------------------------------------
// Gate: 7-tap conv over L of [max, avg] (2 in-channels) + BN(1ch) + ReLU +
// sigmoid, for both channel groups. Grid (B, NLT) x 256.
// ---------------------------------------------------------------------------
__global__ void gate_kernel(const float* __restrict__ cmaxA, const float* __restrict__ cavgA,
                            const float* __restrict__ smaxA, const float* __restrict__ savgA,
                            const float* __restrict__ sa_w,
                            const float* __restrict__ sabn_g, const float* __restrict__ sabn_b,
                            const float* __restrict__ sabn_m, const float* __restrict__ sabn_v,
                            float* __restrict__ A1, float* __restrict__ A2)
{
    int b = blockIdx.x, lt = blockIdx.y;
    int l = lt * 256 + threadIdx.x;
    float inv = sabn_g[0] * rsqrtf(sabn_v[0] + EPSV);
    float bb2 = sabn_b[0] - sabn_m[0] * inv;
    float y1 = 0.0f, y2 = 0.0f;
    #pragma unroll
    for (int k = 0; k < 7; ++k) {
        int ls = l + k - 3;
        if (ls >= 0 && ls < LL) {
            float wm = sa_w[k], wa = sa_w[7 + k];
            y1 = fmaf(wm, cmaxA[b * LL + ls], y1);
            y1 = fmaf(wa, cavgA[b * LL + ls], y1);
            y2 = fmaf(wm, smaxA[b * LL + ls], y2);
            y2 = fmaf(wa, savgA[b * LL + ls], y2);
        }
    }
    float t1 = fmaxf(y1 * inv + bb2, 0.0f);
    float t2 = fmaxf(y2 * inv + bb2, 0.0f);
    A1[b * LL + l] = 1.0f / (1.0f + expf(-t1));
    A2[b * LL + l] = 1.0f / (1.0f + expf(-t2));
}

// ---------------------------------------------------------------------------
// Final: out = f * cm[b,c] * (mask ? A1 : A2), in place on d_out (f lives there).
// ---------------------------------------------------------------------------
__global__ __launch_bounds__(256)
void final_kernel(float* __restrict__ out, const float* __restrict__ cm,
                  const float* __restrict__ maskv,
                  const float* __restrict__ A1, const float* __restrict__ A2)
{
    int g = blockIdx.x * 256 + threadIdx.x;
    size_t idx4 = (size_t)g * 4;
    int l  = (int)(idx4 & (LL - 1));
    int bc = (int)(idx4 >> 14);
    int b  = bc >> 7;
    float cmv = cm[bc];
    float mk  = maskv[bc];
    const float* Ap = (mk > 0.5f) ? A1 : A2;
    float4 a = *(const float4*)&Ap[b * LL + l];
    float4 v = *(const float4*)&out[idx4];
    v.x *= cmv * a.x;
    v.y *= cmv * a.y;
    v.z *= cmv * a.z;
    v.w *= cmv * a.w;
    *(float4*)&out[idx4] = v;
}

extern "C" void kernel_launch(void* const* d_in, const int* in_sizes, int n_in,
                              void* d_out, int out_size, void* d_ws, size_t ws_size,
                              hipStream_t stream)
{
    const float* x      = (const float*)d_in[0];
    const float* conv_w = (const float*)d_in[1];
    const float* conv_b = (const float*)d_in[2];
    const float* bn_g   = (const float*)d_in[3];
    const float* bn_b   = (const float*)d_in[4];
    const float* bn_m   = (const float*)d_in[5];
    const float* bn_v   = (const float*)d_in[6];
    const float* alpha  = (const float*)d_in[7];
    const float* beta   = (const float*)d_in[8];
    const float* ca_w   = (const float*)d_in[9];
    const float* ca_b   = (const float*)d_in[10];
    const float* sa_w   = (const float*)d_in[11];
    const float* sabn_g = (const float*)d_in[12];
    const float* sabn_b = (const float*)d_in[13];
    const float* sabn_m = (const float*)d_in[14];
    const float* sabn_v = (const float*)d_in[15];

    float* out = (float*)d_out;
    float* ws  = (float*)d_ws;

    float* w2    = ws + OFF_W2;
    float* bias2 = ws + OFF_BIAS2;
    float* psum  = ws + OFF_PSUM;
    float* pmax  = ws + OFF_PMAX;
    float* cmv_  = ws + OFF_CM;
    float* mskv  = ws + OFF_MASK;
    float* cmaxA = ws + OFF_CMAX;
    float* cavgA = ws + OFF_CAVG;
    float* smaxA = ws + OFF_SMAX;
    float* savgA = ws + OFF_SAVG;
    float* A1p   = ws + OFF_A1;
    float* A2p   = ws + OFF_A2;

    prep_kernel<<<(IC * KS * CH + 255) / 256, 256, 0, stream>>>(
        conv_w, conv_b, bn_g, bn_b, bn_m, bn_v, w2, bias2);

    conv_kernel<<<dim3(BB, NLT), 256, 0, stream>>>(x, w2, bias2, out, psum, pmax);

    chan_kernel<<<BB, CH, 0, stream>>>(psum, pmax, alpha, beta, ca_w, ca_b, cmv_, mskv);

    stats_kernel<<<dim3(BB, NLT), 256, 0, stream>>>(out, cmv_, mskv, cmaxA, cavgA, smaxA, savgA);

    gate_kernel<<<dim3(BB, NLT), 256, 0, stream>>>(cmaxA, cavgA, smaxA, savgA,
                                                   sa_w, sabn_g, sabn_b, sabn_m, sabn_v, A1p, A2p);

    final_kernel<<<(BB * CH * LL / 4 + 255) / 256, 256, 0, stream>>>(out, cmv_, mskv, A1p, A2p);
}

// Round 2
// 222.997 us; speedup vs baseline: 1.6360x; 1.6360x over previous
//
#include <hip/hip_runtime.h>
#include <hip/hip_bf16.h>
#include <math.h>

#define BB 16
#define IC 64
#define CH 128
#define LL 16384
#define KS 5
#define CAK 5
#define KCR 76
#define EPSV 1e-5f
#define NLT2 256          // psum/pmax partials per (b,c): 128 l-tiles x 2 half-waves

typedef short bf16x8 __attribute__((ext_vector_type(8)));
typedef float f32x16 __attribute__((ext_vector_type(16)));

// ---- workspace layout (in floats) ----
#define OFF_WPACK 0                          // 81920 ushort = 40960 floats
#define OFF_BIAS2 40960                      // 128
#define OFF_PSUM  (OFF_BIAS2 + CH)           // 16*128*256 = 524288
#define OFF_PMAX  (OFF_PSUM + BB*CH*NLT2)
#define OFF_CM    (OFF_PMAX + BB*CH*NLT2)    // 2048
#define OFF_MASK  (OFF_CM + BB*CH)
#define OFF_A1    (OFF_MASK + BB*CH)         // 262144
#define OFF_A2    (OFF_A1 + BB*LL)

__device__ __forceinline__ unsigned short f2bf(float f) {
    union { float f; unsigned u; } v; v.f = f;
    return (unsigned short)((v.u + 0x7FFFu + ((v.u >> 16) & 1u)) >> 16);
}
__device__ __forceinline__ float bf2f(unsigned short h) {
    union { unsigned u; float f; } v; v.u = ((unsigned)h) << 16;
    return v.f;
}

// ---------------------------------------------------------------------------
// Prep: fold BN scale into conv weights, split into bf16 hi/lo, and pack in
// exact per-lane MFMA A-fragment order:
//   wpack[((((ver*2+ch2)*2+mt)*20+s)*64+ln)*8+j]
//     c = ch2*64 + mt*32 + (ln&31); kk = s>>2; i = (s&3)*16 + (ln>>5)*8 + j
// ---------------------------------------------------------------------------
__global__ void prep_kernel(const float* __restrict__ conv_w, const float* __restrict__ conv_b,
                            const float* __restrict__ bn_g, const float* __restrict__ bn_b,
                            const float* __restrict__ bn_m, const float* __restrict__ bn_v,
                            unsigned short* __restrict__ wpack, float* __restrict__ bias2)
{
    int e = blockIdx.x * 256 + threadIdx.x;
    if (e < 2 * 2 * 2 * 20 * 64 * 8) {
        int j    = e & 7;
        int ln   = (e >> 3) & 63;
        int rest = e >> 9;              // 0..159
        int s    = rest % 20;
        int mt   = (rest / 20) & 1;
        int ch2  = (rest / 40) & 1;
        int ver  = rest / 80;
        int c  = ch2 * 64 + mt * 32 + (ln & 31);
        int kk = s >> 2;
        int i  = (s & 3) * 16 + (ln >> 5) * 8 + j;
        float inv = bn_g[c] * rsqrtf(bn_v[c] + EPSV);
        float w = conv_w[(c * IC + i) * KS + kk] * inv;
        unsigned short h = f2bf(w);
        wpack[e] = (ver == 0) ? h : f2bf(w - bf2f(h));
    }
    if (e < CH) {
        float inv = bn_g[e] * rsqrtf(bn_v[e] + EPSV);
        bias2[e] = (conv_b[e] - bn_m[e]) * inv + bn_b[e];
    }
}

// ---------------------------------------------------------------------------
// Split-bf16 MFMA conv + BN + ReLU -> f (fp32, into d_out), plus per-channel
// partial sum/max. Block = 128c x 128l, 4 waves of (64c x 64l).
// f = wh*xh + wh*xl + wl*xh  (fp32 MFMA accumulate; error ~4e-6).
// ---------------------------------------------------------------------------
__global__ __launch_bounds__(256, 2)
void conv_mfma_kernel(const float* __restrict__ x,
                      const unsigned short* __restrict__ wpack,
                      const float* __restrict__ bias2,
                      float* __restrict__ f,
                      float* __restrict__ psum, float* __restrict__ pmax)
{
    __shared__ unsigned short xs[2][136 * 64];   // [hi/lo][l_local][i], XOR-swizzled
    const int b   = blockIdx.x;
    const int lt  = blockIdx.y;
    const int l0  = lt * 128;
    const int tid = threadIdx.x;

    // ---- stage x tile: rows l0-4 .. l0+131 (136), transposed, bf16 hi+lo ----
    const float* xb = x + (size_t)b * (IC * LL);
    for (int t = tid; t < 64 * 34; t += 256) {
        int i  = t / 34;
        int g  = t - i * 34;
        int gl = l0 - 4 + g * 4;
        float4 v = make_float4(0.f, 0.f, 0.f, 0.f);
        if (gl >= 0 && gl + 4 <= LL) v = *(const float4*)(xb + (size_t)i * LL + gl);
        float vv[4] = {v.x, v.y, v.z, v.w};
        #pragma unroll
        for (int j = 0; j < 4; ++j) {
            int row   = g * 4 + j;
            int chunk = (i >> 3) ^ (row & 7);
            int hidx  = row * 64 + chunk * 8 + (i & 7);
            unsigned short h = f2bf(vv[j]);
            xs[0][hidx] = h;
            xs[1][hidx] = f2bf(vv[j] - bf2f(h));
        }
    }
    __syncthreads();

    const int ln   = tid & 63;
    const int wv   = __builtin_amdgcn_readfirstlane(tid >> 6);
    const int ch2  = wv >> 1;   // c-half: 0 -> c 0..63, 1 -> 64..127
    const int lh   = wv & 1;    // l-half within the 128-l tile
    const int ln31 = ln & 31;
    const int hi   = ln >> 5;

    f32x16 acc[2][2];
    #pragma unroll
    for (int mt = 0; mt < 2; ++mt)
        #pragma unroll
        for (int nt = 0; nt < 2; ++nt)
            #pragma unroll
            for (int r = 0; r < 16; ++r) acc[mt][nt][r] = 0.0f;

    const int rowbase = lh * 64 + ln31 + 2;

    #pragma unroll
    for (int pass = 0; pass < 2; ++pass) {     // 0: A=wh (uses bh+bl), 1: A=wl (bh)
        #pragma unroll
        for (int kh = 0; kh < 2; ++kh) {
            bf16x8 a0[10], a1[10];
            #pragma unroll
            for (int ss = 0; ss < 10; ++ss) {
                int s = kh * 10 + ss;
                size_t o0 = ((((size_t)(pass * 2 + ch2) * 2 + 0) * 20 + s) * 64 + ln) * 8;
                size_t o1 = ((((size_t)(pass * 2 + ch2) * 2 + 1) * 20 + s) * 64 + ln) * 8;
                a0[ss] = *(const bf16x8*)(wpack + o0);
                a1[ss] = *(const bf16x8*)(wpack + o1);
            }
            #pragma unroll
            for (int nt = 0; nt < 2; ++nt) {
                #pragma unroll
                for (int ss = 0; ss < 10; ++ss) {
                    int s  = kh * 10 + ss;
                    int kk = s >> 2;
                    int iq = s & 3;
                    int row   = rowbase + nt * 32 + kk;
                    int chunk = (iq * 2 + hi) ^ (row & 7);
                    int hoff  = row * 64 + chunk * 8;
                    bf16x8 bh = *(const bf16x8*)&xs[0][hoff];
                    if (pass == 0) {
                        bf16x8 bl = *(const bf16x8*)&xs[1][hoff];
                        acc[0][nt] = __builtin_amdgcn_mfma_f32_32x32x16_bf16(a0[ss], bh, acc[0][nt], 0, 0, 0);
                        acc[1][nt] = __builtin_amdgcn_mfma_f32_32x32x16_bf16(a1[ss], bh, acc[1][nt], 0, 0, 0);
                        acc[0][nt] = __builtin_amdgcn_mfma_f32_32x32x16_bf16(a0[ss], bl, acc[0][nt], 0, 0, 0);
                        acc[1][nt] = __builtin_amdgcn_mfma_f32_32x32x16_bf16(a1[ss], bl, acc[1][nt], 0, 0, 0);
                    } else {
                        acc[0][nt] = __builtin_amdgcn_mfma_f32_32x32x16_bf16(a0[ss], bh, acc[0][nt], 0, 0, 0);
                        acc[1][nt] = __builtin_amdgcn_mfma_f32_32x32x16_bf16(a1[ss], bh, acc[1][nt], 0, 0, 0);
                    }
                }
            }
        }
    }

    // ---- epilogue: bias + relu, store f, per-channel partial sum/max ----
    // D mapping (32x32): col(l) = ln&31, row(c) = (r&3) + 8*(r>>2) + 4*(ln>>5)
    const int lgbase = l0 + lh * 64 + ln31;
    #pragma unroll
    for (int mt = 0; mt < 2; ++mt) {
        #pragma unroll
        for (int nt = 0; nt < 2; ++nt) {
            #pragma unroll
            for (int r = 0; r < 16; ++r) {
                int c = ch2 * 64 + mt * 32 + (r & 3) + 8 * (r >> 2) + 4 * hi;
                float fv = fmaxf(acc[mt][nt][r] + bias2[c], 0.0f);
                f[((size_t)(b * CH + c)) * LL + lgbase + nt * 32] = fv;
                acc[mt][nt][r] = fv;
            }
        }
    }
    #pragma unroll
    for (int mt = 0; mt < 2; ++mt) {
        #pragma unroll
        for (int r = 0; r < 16; ++r) {
            float s = acc[mt][0][r] + acc[mt][1][r];
            float m = fmaxf(acc[mt][0][r], acc[mt][1][r]);
            #pragma unroll
            for (int off = 1; off <= 16; off <<= 1) {
                s += __shfl_xor(s, off, 64);
                m = fmaxf(m, __shfl_xor(m, off, 64));
            }
            if (ln31 == 0) {
                int c   = ch2 * 64 + mt * 32 + (r & 3) + 8 * (r >> 2) + 4 * hi;
                int lt2 = lt * 2 + lh;
                psum[(b * CH + c) * NLT2 + lt2] = s;
                pmax[(b * CH + c) * NLT2 + lt2] = m;
            }
        }
    }
}

// ---------------------------------------------------------------------------
// Per-batch: finish L-reductions, channel attention, top-K mask (rank count,
// ties by lower index to match jax.lax.top_k). Grid: B x 128 threads.
// ---------------------------------------------------------------------------
__global__ void chan_kernel(const float* __restrict__ psum, const float* __restrict__ pmax,
                            const float* __restrict__ alpha, const float* __restrict__ beta,
                            const float* __restrict__ ca_w, const float* __restrict__ ca_b,
                            float* __restrict__ cm, float* __restrict__ maskv)
{
    int b = blockIdx.x;
    int c = threadIdx.x;   // 128
    const float* ps = psum + (b * CH + c) * NLT2;
    const float* pm = pmax + (b * CH + c) * NLT2;
    float s = 0.0f, m = 0.0f;
    for (int t = 0; t < NLT2; ++t) { s += ps[t]; m = fmaxf(m, pm[t]); }
    float favg = s * (1.0f / LL);
    float fadd = (alpha[0] + 0.5f) * favg + (beta[0] + 0.5f) * m;

    __shared__ float fa[CH];
    __shared__ float cms[CH];
    fa[c] = fadd;
    __syncthreads();

    float z = ca_b[0];
    #pragma unroll
    for (int k = 0; k < CAK; ++k) {
        int cc = c + k - 2;
        float v = (cc >= 0 && cc < CH) ? fa[cc] : 0.0f;
        z = fmaf(ca_w[k], v, z);
    }
    float cmv = 1.0f / (1.0f + expf(-z));
    cms[c] = cmv;
    __syncthreads();

    int rank = 0;
    for (int cc = 0; cc < CH; ++cc) {
        float o = cms[cc];
        rank += (o > cmv || (o == cmv && cc < c)) ? 1 : 0;
    }
    cm[b * CH + c] = cmv;
    maskv[b * CH + c] = (rank < KCR) ? 1.0f : 0.0f;
}

// ---------------------------------------------------------------------------
// Fused stats + gate: per (b,l) cross-channel group stats of crf = f*cm, with
// +/-3 halo recomputed locally (f untouched), then the 7-tap gate conv + BN +
// ReLU + sigmoid -> A1, A2. Grid (B, 64) x 256.
// ---------------------------------------------------------------------------
__global__ __launch_bounds__(256)
void stats_gate_kernel(const float* __restrict__ f, const float* __restrict__ cm,
                       const float* __restrict__ maskv, const float* __restrict__ sa_w,
                       const float* __restrict__ sabn_g, const float* __restrict__ sabn_b,
                       const float* __restrict__ sabn_m, const float* __restrict__ sabn_v,
                       float* __restrict__ A1, float* __restrict__ A2)
{
    __shared__ float cms[CH], mks[CH];
    __shared__ float st[4][264];
    int b   = blockIdx.x;
    int l0  = blockIdx.y * 256;
    int tid = threadIdx.x;
    if (tid < CH) { cms[tid] = cm[b * CH + tid]; mks[tid] = maskv[b * CH + tid]; }
    __syncthreads();

    for (int idx = tid; idx < 262; idx += 256) {
        int l = l0 - 3 + idx;
        float cmx = 0.f, csm = 0.f, smx = 0.f, ssm = 0.f;
        if (l >= 0 && l < LL) {
            const float* fb = f + (size_t)b * CH * LL + l;
            #pragma unroll 4
            for (int c = 0; c < CH; ++c) {
                float v  = fb[(size_t)c * LL] * cms[c];
                float mk = mks[c];
                float vs = v * mk;
                float vu = v - vs;
                cmx = fmaxf(cmx, vs);
                smx = fmaxf(smx, vu);
                csm += vs;
                ssm += vu;
            }
        }
        st[0][idx] = cmx;
        st[1][idx] = csm * (1.0f / KCR);
        st[2][idx] = smx;
        st[3][idx] = ssm * (1.0f / (CH - KCR));
    }
    __syncthreads();

    float inv = sabn_g[0] * rsqrtf(sabn_v[0] + EPSV);
    float bb2 = sabn_b[0] - sabn_m[0] * inv;
    float y1 = 0.f, y2 = 0.f;
    #pragma unroll
    for (int k = 0; k < 7; ++k) {
        float wm = sa_w[k], wa = sa_w[7 + k];
        y1 = fmaf(wm, st[0][tid + k], fmaf(wa, st[1][tid + k], y1));
        y2 = fmaf(wm, st[2][tid + k], fmaf(wa, st[3][tid + k], y2));
    }
    float t1 = fmaxf(y1 * inv + bb2, 0.f);
    float t2 = fmaxf(y2 * inv + bb2, 0.f);
    A1[b * LL + l0 + tid] = 1.0f / (1.0f + expf(-t1));
    A2[b * LL + l0 + tid] = 1.0f / (1.0f + expf(-t2));
}

// ---------------------------------------------------------------------------
// Final: out = f * cm[b,c] * (mask ? A1 : A2), in place on d_out.
// ---------------------------------------------------------------------------
__global__ __launch_bounds__(256)
void final_kernel(float* __restrict__ out, const float* __restrict__ cm,
                  const float* __restrict__ maskv,
                  const float* __restrict__ A1, const float* __restrict__ A2)
{
    int g = blockIdx.x * 256 + threadIdx.x;
    size_t idx4 = (size_t)g * 4;
    int l  = (int)(idx4 & (LL - 1));
    int bc = (int)(idx4 >> 14);
    int b  = bc >> 7;
    float cmv = cm[bc];
    float mk  = maskv[bc];
    const float* Ap = (mk > 0.5f) ? A1 : A2;
    float4 a = *(const float4*)&Ap[b * LL + l];
    float4 v = *(const float4*)&out[idx4];
    v.x *= cmv * a.x;
    v.y *= cmv * a.y;
    v.z *= cmv * a.z;
    v.w *= cmv * a.w;
    *(float4*)&out[idx4] = v;
}

extern "C" void kernel_launch(void* const* d_in, const int* in_sizes, int n_in,
                              void* d_out, int out_size, void* d_ws, size_t ws_size,
                              hipStream_t stream)
{
    const float* x      = (const float*)d_in[0];
    const float* conv_w = (const float*)d_in[1];
    const float* conv_b = (const float*)d_in[2];
    const float* bn_g   = (const float*)d_in[3];
    const float* bn_b   = (const float*)d_in[4];
    const float* bn_m   = (const float*)d_in[5];
    const float* bn_v   = (const float*)d_in[6];
    const float* alpha  = (const float*)d_in[7];
    const float* beta   = (const float*)d_in[8];
    const float* ca_w   = (const float*)d_in[9];
    const float* ca_b   = (const float*)d_in[10];
    const float* sa_w   = (const float*)d_in[11];
    const float* sabn_g = (const float*)d_in[12];
    const float* sabn_b = (const float*)d_in[13];
    const float* sabn_m = (const float*)d_in[14];
    const float* sabn_v = (const float*)d_in[15];

    float* out = (float*)d_out;
    float* ws  = (float*)d_ws;

    unsigned short* wpack = (unsigned short*)(ws + OFF_WPACK);
    float* bias2 = ws + OFF_BIAS2;
    float* psum  = ws + OFF_PSUM;
    float* pmax  = ws + OFF_PMAX;
    float* cmv_  = ws + OFF_CM;
    float* mskv  = ws + OFF_MASK;
    float* A1p   = ws + OFF_A1;
    float* A2p   = ws + OFF_A2;

    prep_kernel<<<320, 256, 0, stream>>>(conv_w, conv_b, bn_g, bn_b, bn_m, bn_v, wpack, bias2);

    conv_mfma_kernel<<<dim3(BB, 128), 256, 0, stream>>>(x, wpack, bias2, out, psum, pmax);

    chan_kernel<<<BB, CH, 0, stream>>>(psum, pmax, alpha, beta, ca_w, ca_b, cmv_, mskv);

    stats_gate_kernel<<<dim3(BB, 64), 256, 0, stream>>>(out, cmv_, mskv, sa_w,
                                                        sabn_g, sabn_b, sabn_m, sabn_v, A1p, A2p);

    final_kernel<<<(BB * CH * LL / 4 + 255) / 256, 256, 0, stream>>>(out, cmv_, mskv, A1p, A2p);
}

// Round 3
// 190.687 us; speedup vs baseline: 1.9132x; 1.1694x over previous
//
#include <hip/hip_runtime.h>
#include <hip/hip_bf16.h>
#include <math.h>

#define BB 16
#define IC 64
#define CH 128
#define LL 16384
#define KS 5
#define CAK 5
#define KCR 76
#define EPSV 1e-5f
#define NLT2 256          // psum/pmax partials per (b,c): 128 l-tiles x 2 half-waves

typedef short bf16x8 __attribute__((ext_vector_type(8)));
typedef float f32x16 __attribute__((ext_vector_type(16)));

// ---- workspace layout (in floats) ----
#define OFF_WPACK 0                          // 81920 ushort = 40960 floats
#define OFF_BIAS2 40960                      // 128
#define OFF_PSUM  (OFF_BIAS2 + CH)           // 16*128*256 = 524288
#define OFF_PMAX  (OFF_PSUM + BB*CH*NLT2)
#define OFF_CM    (OFF_PMAX + BB*CH*NLT2)    // 2048
#define OFF_MASK  (OFF_CM + BB*CH)
#define OFF_A1    (OFF_MASK + BB*CH)         // 262144
#define OFF_A2    (OFF_A1 + BB*LL)

__device__ __forceinline__ unsigned short f2bf(float f) {
    union { float f; unsigned u; } v; v.f = f;
    return (unsigned short)((v.u + 0x7FFFu + ((v.u >> 16) & 1u)) >> 16);
}
__device__ __forceinline__ float bf2f(unsigned short h) {
    union { unsigned u; float f; } v; v.u = ((unsigned)h) << 16;
    return v.f;
}

// ---------------------------------------------------------------------------
// Prep: fold BN scale into conv weights, split into bf16 hi/lo, pack in exact
// per-lane MFMA A-fragment order (same layout as round 2):
//   wpack[((((ver*2+ch2)*2+mt)*20+s)*64+ln)*8+j]
//     c = ch2*64 + mt*32 + (ln&31); kk = s>>2; i = (s&3)*16 + (ln>>5)*8 + j
// ---------------------------------------------------------------------------
__global__ void prep_kernel(const float* __restrict__ conv_w, const float* __restrict__ conv_b,
                            const float* __restrict__ bn_g, const float* __restrict__ bn_b,
                            const float* __restrict__ bn_m, const float* __restrict__ bn_v,
                            unsigned short* __restrict__ wpack, float* __restrict__ bias2)
{
    int e = blockIdx.x * 256 + threadIdx.x;
    if (e < 2 * 2 * 2 * 20 * 64 * 8) {
        int j    = e & 7;
        int ln   = (e >> 3) & 63;
        int rest = e >> 9;              // 0..159
        int s    = rest % 20;
        int mt   = (rest / 20) & 1;
        int ch2  = (rest / 40) & 1;
        int ver  = rest / 80;
        int c  = ch2 * 64 + mt * 32 + (ln & 31);
        int kk = s >> 2;
        int i  = (s & 3) * 16 + (ln >> 5) * 8 + j;
        float inv = bn_g[c] * rsqrtf(bn_v[c] + EPSV);
        float w = conv_w[(c * IC + i) * KS + kk] * inv;
        unsigned short h = f2bf(w);
        wpack[e] = (ver == 0) ? h : f2bf(w - bf2f(h));
    }
    if (e < CH) {
        float inv = bn_g[e] * rsqrtf(bn_v[e] + EPSV);
        bias2[e] = (conv_b[e] - bn_m[e]) * inv + bn_b[e];
    }
}

// ---------------------------------------------------------------------------
// Split-bf16 MFMA conv + BN + ReLU -> f (fp32, into d_out) + per-channel
// partial sum/max. Block = 128c x 128l, 4 waves of (64c x 64l).
// LDS tile xs[136 rows(l)][128] = [64 hi bf16 | 64 lo bf16], 16B chunks
// XOR-swizzled by (row&7). Staged with coalesced global reads (lane = l) and
// conflict-free ds_write_b64. Main loop: per K-slice s, read bh/bl once and
// run all 12 MFMAs (wh*xh, wh*xl, wl*xh merged); A-frags prefetched.
// ---------------------------------------------------------------------------
__global__ __launch_bounds__(256, 3)
void conv_mfma_kernel(const float* __restrict__ x,
                      const unsigned short* __restrict__ wpack,
                      const float* __restrict__ bias2,
                      float* __restrict__ f,
                      float* __restrict__ psum, float* __restrict__ pmax)
{
    __shared__ unsigned short xs[136 * 128];   // 34,816 B
    const int b   = blockIdx.x;
    const int lt  = blockIdx.y;
    const int l0  = lt * 128;
    const int tid = threadIdx.x;
    const int ln  = tid & 63;
    const int wv  = __builtin_amdgcn_readfirstlane(tid >> 6);

    // ---- staging: wave wv owns i in [wv*16, wv*16+16); lane = row (l) ----
    const float* xb = x + (size_t)b * (IC * LL);
    const int ibase = wv * 16;
    #pragma unroll
    for (int g = 0; g < 3; ++g) {
        int row = g * 64 + ln;           // 0..191; valid rows < 136
        int l   = l0 - 4 + row;
        if (row < 136) {
            bool vl = (l >= 0) && (l < LL);
            float v[16];
            #pragma unroll
            for (int q = 0; q < 16; ++q)
                v[q] = vl ? xb[(size_t)(ibase + q) * LL + l] : 0.0f;
            int rs = row & 7;
            #pragma unroll
            for (int q2 = 0; q2 < 4; ++q2) {
                unsigned short h[4], lo[4];
                #pragma unroll
                for (int j = 0; j < 4; ++j) {
                    float vv = v[q2 * 4 + j];
                    h[j]  = f2bf(vv);
                    lo[j] = f2bf(vv - bf2f(h[j]));
                }
                int i0   = ibase + q2 * 4;
                int cc   = (i0 >> 3) ^ rs;
                int epos = row * 128 + cc * 8 + (i0 & 7);
                uint2 wh, wl;
                wh.x = (unsigned)h[0]  | ((unsigned)h[1]  << 16);
                wh.y = (unsigned)h[2]  | ((unsigned)h[3]  << 16);
                wl.x = (unsigned)lo[0] | ((unsigned)lo[1] << 16);
                wl.y = (unsigned)lo[2] | ((unsigned)lo[3] << 16);
                *(uint2*)&xs[epos]      = wh;
                *(uint2*)&xs[epos + 64] = wl;
            }
        }
    }
    __syncthreads();

    const int ch2  = wv >> 1;   // c-half: 0 -> c 0..63, 1 -> 64..127
    const int lh   = wv & 1;    // l-half within the 128-l tile
    const int ln31 = ln & 31;
    const int hi   = ln >> 5;
    const int rowbase = lh * 64 + ln31 + 2;

    // A-fragment stream pointers (wpack is L2-hot, 160 KB)
    const unsigned short* wp  = wpack + (size_t)ln * 8;
    const unsigned short* pA0 = wp + (size_t)((ch2 * 2 + 0) * 20) * 512;       // wh, mt0
    const unsigned short* pA1 = wp + (size_t)((ch2 * 2 + 1) * 20) * 512;       // wh, mt1
    const unsigned short* pA2 = wp + (size_t)(((2 + ch2) * 2 + 0) * 20) * 512; // wl, mt0
    const unsigned short* pA3 = wp + (size_t)(((2 + ch2) * 2 + 1) * 20) * 512; // wl, mt1

    f32x16 acc[2][2];
    #pragma unroll
    for (int mt = 0; mt < 2; ++mt)
        #pragma unroll
        for (int nt = 0; nt < 2; ++nt)
            #pragma unroll
            for (int r = 0; r < 16; ++r) acc[mt][nt][r] = 0.0f;

    auto loadA = [&](bf16x8* Av, int s) {
        Av[0] = *(const bf16x8*)(pA0 + (size_t)s * 512);
        Av[1] = *(const bf16x8*)(pA1 + (size_t)s * 512);
        Av[2] = *(const bf16x8*)(pA2 + (size_t)s * 512);
        Av[3] = *(const bf16x8*)(pA3 + (size_t)s * 512);
    };
    auto loadB = [&](bf16x8* Bv, int s) {
        int kk = s >> 2, iq = s & 3;
        int r0 = rowbase + kk;
        int r1 = r0 + 32;
        int c0 = ((iq << 1) + hi) ^ (r0 & 7);
        int c1 = ((iq << 1) + hi) ^ (r1 & 7);
        Bv[0] = *(const bf16x8*)&xs[r0 * 128 + c0 * 8];        // bh, nt0
        Bv[1] = *(const bf16x8*)&xs[r0 * 128 + 64 + c0 * 8];   // bl, nt0
        Bv[2] = *(const bf16x8*)&xs[r1 * 128 + c1 * 8];        // bh, nt1
        Bv[3] = *(const bf16x8*)&xs[r1 * 128 + 64 + c1 * 8];   // bl, nt1
    };
    auto compute = [&](const bf16x8* Av, const bf16x8* Bv) {
        acc[0][0] = __builtin_amdgcn_mfma_f32_32x32x16_bf16(Av[0], Bv[0], acc[0][0], 0, 0, 0);
        acc[1][0] = __builtin_amdgcn_mfma_f32_32x32x16_bf16(Av[1], Bv[0], acc[1][0], 0, 0, 0);
        acc[0][0] = __builtin_amdgcn_mfma_f32_32x32x16_bf16(Av[0], Bv[1], acc[0][0], 0, 0, 0);
        acc[1][0] = __builtin_amdgcn_mfma_f32_32x32x16_bf16(Av[1], Bv[1], acc[1][0], 0, 0, 0);
        acc[0][0] = __builtin_amdgcn_mfma_f32_32x32x16_bf16(Av[2], Bv[0], acc[0][0], 0, 0, 0);
        acc[1][0] = __builtin_amdgcn_mfma_f32_32x32x16_bf16(Av[3], Bv[0], acc[1][0], 0, 0, 0);
        acc[0][1] = __builtin_amdgcn_mfma_f32_32x32x16_bf16(Av[0], Bv[2], acc[0][1], 0, 0, 0);
        acc[1][1] = __builtin_amdgcn_mfma_f32_32x32x16_bf16(Av[1], Bv[2], acc[1][1], 0, 0, 0);
        acc[0][1] = __builtin_amdgcn_mfma_f32_32x32x16_bf16(Av[0], Bv[3], acc[0][1], 0, 0, 0);
        acc[1][1] = __builtin_amdgcn_mfma_f32_32x32x16_bf16(Av[1], Bv[3], acc[1][1], 0, 0, 0);
        acc[0][1] = __builtin_amdgcn_mfma_f32_32x32x16_bf16(Av[2], Bv[2], acc[0][1], 0, 0, 0);
        acc[1][1] = __builtin_amdgcn_mfma_f32_32x32x16_bf16(Av[3], Bv[2], acc[1][1], 0, 0, 0);
    };

    bf16x8 Aa[4], Ab[4], Ba[4], Bb[4];
    loadA(Aa, 0); loadB(Ba, 0);
    for (int s2 = 0; s2 < 10; ++s2) {
        int s = 2 * s2;
        loadA(Ab, s + 1); loadB(Bb, s + 1);
        compute(Aa, Ba);
        int sn = (s + 2 < 20) ? (s + 2) : 19;   // clamped prefetch (unused on last iter)
        loadA(Aa, sn); loadB(Ba, sn);
        compute(Ab, Bb);
    }

    // ---- epilogue: bias + relu, store f, per-channel partial sum/max ----
    // D mapping (32x32): col(l) = ln&31, row(c) = (r&3) + 8*(r>>2) + 4*(ln>>5)
    const int lgbase = l0 + lh * 64 + ln31;
    #pragma unroll
    for (int mt = 0; mt < 2; ++mt) {
        #pragma unroll
        for (int nt = 0; nt < 2; ++nt) {
            #pragma unroll
            for (int r = 0; r < 16; ++r) {
                int c = ch2 * 64 + mt * 32 + (r & 3) + 8 * (r >> 2) + 4 * hi;
                float fv = fmaxf(acc[mt][nt][r] + bias2[c], 0.0f);
                f[((size_t)(b * CH + c)) * LL + lgbase + nt * 32] = fv;
                acc[mt][nt][r] = fv;
            }
        }
    }
    #pragma unroll
    for (int mt = 0; mt < 2; ++mt) {
        #pragma unroll
        for (int r = 0; r < 16; ++r) {
            float s = acc[mt][0][r] + acc[mt][1][r];
            float m = fmaxf(acc[mt][0][r], acc[mt][1][r]);
            #pragma unroll
            for (int off = 1; off <= 16; off <<= 1) {
                s += __shfl_xor(s, off, 64);
                m = fmaxf(m, __shfl_xor(m, off, 64));
            }
            if (ln31 == 0) {
                int c   = ch2 * 64 + mt * 32 + (r & 3) + 8 * (r >> 2) + 4 * hi;
                int lt2 = lt * 2 + lh;
                psum[(b * CH + c) * NLT2 + lt2] = s;
                pmax[(b * CH + c) * NLT2 + lt2] = m;
            }
        }
    }
}

// ---------------------------------------------------------------------------
// Per-batch: finish L-reductions, channel attention, top-K mask (rank count,
// ties by lower index to match jax.lax.top_k). Grid: B x 128 threads.
// ---------------------------------------------------------------------------
__global__ void chan_kernel(const float* __restrict__ psum, const float* __restrict__ pmax,
                            const float* __restrict__ alpha, const float* __restrict__ beta,
                            const float* __restrict__ ca_w, const float* __restrict__ ca_b,
                            float* __restrict__ cm, float* __restrict__ maskv)
{
    int b = blockIdx.x;
    int c = threadIdx.x;   // 128
    const float* ps = psum + (b * CH + c) * NLT2;
    const float* pm = pmax + (b * CH + c) * NLT2;
    float s = 0.0f, m = 0.0f;
    for (int t = 0; t < NLT2; ++t) { s += ps[t]; m = fmaxf(m, pm[t]); }
    float favg = s * (1.0f / LL);
    float fadd = (alpha[0] + 0.5f) * favg + (beta[0] + 0.5f) * m;

    __shared__ float fa[CH];
    __shared__ float cms[CH];
    fa[c] = fadd;
    __syncthreads();

    float z = ca_b[0];
    #pragma unroll
    for (int k = 0; k < CAK; ++k) {
        int cc = c + k - 2;
        float v = (cc >= 0 && cc < CH) ? fa[cc] : 0.0f;
        z = fmaf(ca_w[k], v, z);
    }
    float cmv = 1.0f / (1.0f + expf(-z));
    cms[c] = cmv;
    __syncthreads();

    int rank = 0;
    for (int cc = 0; cc < CH; ++cc) {
        float o = cms[cc];
        rank += (o > cmv || (o == cmv && cc < c)) ? 1 : 0;
    }
    cm[b * CH + c] = cmv;
    maskv[b * CH + c] = (rank < KCR) ? 1.0f : 0.0f;
}

// ---------------------------------------------------------------------------
// Fused stats + gate: per (b,l) cross-channel group stats of crf = f*cm, with
// +/-3 halo recomputed locally (f untouched), then the 7-tap gate conv + BN +
// ReLU + sigmoid -> A1, A2. Grid (B, 64) x 256.
// ---------------------------------------------------------------------------
__global__ __launch_bounds__(256)
void stats_gate_kernel(const float* __restrict__ f, const float* __restrict__ cm,
                       const float* __restrict__ maskv, const float* __restrict__ sa_w,
                       const float* __restrict__ sabn_g, const float* __restrict__ sabn_b,
                       const float* __restrict__ sabn_m, const float* __restrict__ sabn_v,
                       float* __restrict__ A1, float* __restrict__ A2)
{
    __shared__ float cms[CH], mks[CH];
    __shared__ float st[4][264];
    int b   = blockIdx.x;
    int l0  = blockIdx.y * 256;
    int tid = threadIdx.x;
    if (tid < CH) { cms[tid] = cm[b * CH + tid]; mks[tid] = maskv[b * CH + tid]; }
    __syncthreads();

    for (int idx = tid; idx < 262; idx += 256) {
        int l = l0 - 3 + idx;
        float cmx = 0.f, csm = 0.f, smx = 0.f, ssm = 0.f;
        if (l >= 0 && l < LL) {
            const float* fb = f + (size_t)b * CH * LL + l;
            #pragma unroll 4
            for (int c = 0; c < CH; ++c) {
                float v  = fb[(size_t)c * LL] * cms[c];
                float mk = mks[c];
                float vs = v * mk;
                float vu = v - vs;
                cmx = fmaxf(cmx, vs);
                smx = fmaxf(smx, vu);
                csm += vs;
                ssm += vu;
            }
        }
        st[0][idx] = cmx;
        st[1][idx] = csm * (1.0f / KCR);
        st[2][idx] = smx;
        st[3][idx] = ssm * (1.0f / (CH - KCR));
    }
    __syncthreads();

    float inv = sabn_g[0] * rsqrtf(sabn_v[0] + EPSV);
    float bb2 = sabn_b[0] - sabn_m[0] * inv;
    float y1 = 0.f, y2 = 0.f;
    #pragma unroll
    for (int k = 0; k < 7; ++k) {
        float wm = sa_w[k], wa = sa_w[7 + k];
        y1 = fmaf(wm, st[0][tid + k], fmaf(wa, st[1][tid + k], y1));
        y2 = fmaf(wm, st[2][tid + k], fmaf(wa, st[3][tid + k], y2));
    }
    float t1 = fmaxf(y1 * inv + bb2, 0.f);
    float t2 = fmaxf(y2 * inv + bb2, 0.f);
    A1[b * LL + l0 + tid] = 1.0f / (1.0f + expf(-t1));
    A2[b * LL + l0 + tid] = 1.0f / (1.0f + expf(-t2));
}

// ---------------------------------------------------------------------------
// Final: out = f * cm[b,c] * (mask ? A1 : A2), in place on d_out.
// ---------------------------------------------------------------------------
__global__ __launch_bounds__(256)
void final_kernel(float* __restrict__ out, const float* __restrict__ cm,
                  const float* __restrict__ maskv,
                  const float* __restrict__ A1, const float* __restrict__ A2)
{
    int g = blockIdx.x * 256 + threadIdx.x;
    size_t idx4 = (size_t)g * 4;
    int l  = (int)(idx4 & (LL - 1));
    int bc = (int)(idx4 >> 14);
    int b  = bc >> 7;
    float cmv = cm[bc];
    float mk  = maskv[bc];
    const float* Ap = (mk > 0.5f) ? A1 : A2;
    float4 a = *(const float4*)&Ap[b * LL + l];
    float4 v = *(const float4*)&out[idx4];
    v.x *= cmv * a.x;
    v.y *= cmv * a.y;
    v.z *= cmv * a.z;
    v.w *= cmv * a.w;
    *(float4*)&out[idx4] = v;
}

extern "C" void kernel_launch(void* const* d_in, const int* in_sizes, int n_in,
                              void* d_out, int out_size, void* d_ws, size_t ws_size,
                              hipStream_t stream)
{
    const float* x      = (const float*)d_in[0];
    const float* conv_w = (const float*)d_in[1];
    const float* conv_b = (const float*)d_in[2];
    const float* bn_g   = (const float*)d_in[3];
    const float* bn_b   = (const float*)d_in[4];
    const float* bn_m   = (const float*)d_in[5];
    const float* bn_v   = (const float*)d_in[6];
    const float* alpha  = (const float*)d_in[7];
    const float* beta   = (const float*)d_in[8];
    const float* ca_w   = (const float*)d_in[9];
    const float* ca_b   = (const float*)d_in[10];
    const float* sa_w   = (const float*)d_in[11];
    const float* sabn_g = (const float*)d_in[12];
    const float* sabn_b = (const float*)d_in[13];
    const float* sabn_m = (const float*)d_in[14];
    const float* sabn_v = (const float*)d_in[15];

    float* out = (float*)d_out;
    float* ws  = (float*)d_ws;

    unsigned short* wpack = (unsigned short*)(ws + OFF_WPACK);
    float* bias2 = ws + OFF_BIAS2;
    float* psum  = ws + OFF_PSUM;
    float* pmax  = ws + OFF_PMAX;
    float* cmv_  = ws + OFF_CM;
    float* mskv  = ws + OFF_MASK;
    float* A1p   = ws + OFF_A1;
    float* A2p   = ws + OFF_A2;

    prep_kernel<<<320, 256, 0, stream>>>(conv_w, conv_b, bn_g, bn_b, bn_m, bn_v, wpack, bias2);

    conv_mfma_kernel<<<dim3(BB, 128), 256, 0, stream>>>(x, wpack, bias2, out, psum, pmax);

    chan_kernel<<<BB, CH, 0, stream>>>(psum, pmax, alpha, beta, ca_w, ca_b, cmv_, mskv);

    stats_gate_kernel<<<dim3(BB, 64), 256, 0, stream>>>(out, cmv_, mskv, sa_w,
                                                        sabn_g, sabn_b, sabn_m, sabn_v, A1p, A2p);

    final_kernel<<<(BB * CH * LL / 4 + 255) / 256, 256, 0, stream>>>(out, cmv_, mskv, A1p, A2p);
}